// Round 2
// baseline (154.483 us; speedup 1.0000x reference)
//
#include <hip/hip_runtime.h>

#define NN 2048

typedef unsigned short u16;
typedef __attribute__((ext_vector_type(8))) short short8;
typedef __attribute__((ext_vector_type(4))) float floatx4;

__device__ __forceinline__ u16 f2bf(float f) {
  unsigned u = __float_as_uint(f);
  u += 0x7FFF + ((u >> 16) & 1);   // RNE
  return (u16)(u >> 16);
}

__device__ __forceinline__ float bf2f(u16 h) {
  return __uint_as_float(((unsigned)h) << 16);
}

// async global->LDS, 16B per lane. LDS dest = wave-uniform base + lane*16.
__device__ __forceinline__ void load_lds16(const u16* g, u16* l) {
  __builtin_amdgcn_global_load_lds(
      (const __attribute__((address_space(1))) unsigned int*)g,
      (__attribute__((address_space(3))) unsigned int*)l,
      16, 0, 0);
}

// ---------------------------------------------------------------------------
// prep: fp32 -> bf16 (Abf row-major + AbfT transposed), fp32 row-sum partials
// degp[mat][row][32] (contiguous per row for finalize), zero tri.
// grid (32,32,2), block 256. Tile 64x64.
// ---------------------------------------------------------------------------
__global__ __launch_bounds__(256) void prep_kernel(
    const float* __restrict__ A1, const float* __restrict__ A2,
    u16* __restrict__ Abf, u16* __restrict__ AbfT,
    float* __restrict__ degp, float* __restrict__ tri) {
  __shared__ u16 Tl[64][68];  // pad 4 -> 4-way max on transposed reads
  const int bx = blockIdx.x, by = blockIdx.y, bz = blockIdx.z;
  const float* __restrict__ A = bz ? A2 : A1;
  u16* __restrict__ ab = Abf + (size_t)bz * (NN * (size_t)NN);
  u16* __restrict__ at = AbfT + (size_t)bz * (NN * (size_t)NN);
  float* __restrict__ dp = degp + (size_t)bz * (32 * NN);
  const int t = threadIdx.x;
  const int r0 = by * 64, c0 = bx * 64;
  const int rs = t >> 4, cs = t & 15;

  if (bx == 0 && t < 64) tri[bz * NN + by * 64 + t] = 0.f;

#pragma unroll
  for (int it = 0; it < 4; ++it) {
    const int r = it * 16 + rs;
    const float4 fv = *(const float4*)(A + (size_t)(r0 + r) * NN + c0 + cs * 4);
    ushort4 b;
    b.x = f2bf(fv.x); b.y = f2bf(fv.y); b.z = f2bf(fv.z); b.w = f2bf(fv.w);
    *(ushort4*)(ab + (size_t)(r0 + r) * NN + c0 + cs * 4) = b;
    Tl[r][cs * 4 + 0] = b.x; Tl[r][cs * 4 + 1] = b.y;
    Tl[r][cs * 4 + 2] = b.z; Tl[r][cs * 4 + 3] = b.w;
    // exact fp32 row-sum partial over this 64-col slab
    float s = fv.x + fv.y + fv.z + fv.w;
    s += __shfl_xor(s, 1); s += __shfl_xor(s, 2);
    s += __shfl_xor(s, 4); s += __shfl_xor(s, 8);
    if (cs == 0) dp[(r0 + r) * 32 + bx] = s;
  }
  __syncthreads();
#pragma unroll
  for (int it = 0; it < 4; ++it) {
    const int c = it * 16 + rs;
    ushort4 b;
    b.x = Tl[cs * 4 + 0][c]; b.y = Tl[cs * 4 + 1][c];
    b.z = Tl[cs * 4 + 2][c]; b.w = Tl[cs * 4 + 3][c];
    *(ushort4*)(at + (size_t)(c0 + c) * NN + r0 + cs * 4) = b;
  }
}

// ---------------------------------------------------------------------------
// gemm_tri: tri[i] += sum_j (A@A)_{ij} * A_{ji}, fused; never materializes A@A.
// Split-K=2: blockIdx.z = mat*2 + kz, each block does K-half [kz*1024, +1024).
// 128x128 C-tile per block, BK=32, 4 waves (2x2), 4x4 MFMA 16x16x32 per wave.
// Staging: global_load_lds w16, XOR chunk swizzle applied on GLOBAL side so
// LDS stays lane-contiguous; frag ds_read_b128 lands at 2-way conflict (free).
// grid (16,16,4), block 256. 4 blocks/CU (LDS 34816*4 = 139 KB).
// ---------------------------------------------------------------------------
__global__ __launch_bounds__(256) void gemm_tri_kernel(
    const u16* __restrict__ Abf, const u16* __restrict__ AbfT,
    float* __restrict__ tri) {
  __shared__ u16 smem[17408];  // loop: As[0..4096) Bs[4096..8192); epi: T 128x136

  const int tid = threadIdx.x;
  const int w = tid >> 6, lane = tid & 63;
  const int wm = w >> 1, wn = w & 1;
  const int cl = lane & 15, g = lane >> 4;
  const int i0 = blockIdx.y * 128, j0 = blockIdx.x * 128;
  const int mz = blockIdx.z >> 1, kz = blockIdx.z & 1;
  const size_t mat = (size_t)mz * (NN * (size_t)NN);
  const u16* __restrict__ Am = Abf + mat;
  const u16* __restrict__ ATm = AbfT + mat;
  float* __restrict__ triM = tri + mz * NN;

  // staging descriptors: wave w issues 2 calls for As, 2 for Bs per K-step.
  // LDS slot s (16B) -> row = s>>2, stored-chunk c' = s&3 holds global chunk
  // c = c' ^ ((row>>1)&3)   (swizzle so frag reads are ~conflict-free)
  const int s0 = (w * 2 + 0) * 64 + lane;
  const int s1 = (w * 2 + 1) * 64 + lane;
  const int r0s = s0 >> 2, c0s = (s0 & 3) ^ ((r0s >> 1) & 3);
  const int r1s = s1 >> 2, c1s = (s1 & 3) ^ ((r1s >> 1) & 3);
  const int kbase = kz * 1024;
  const u16* gA0 = Am + (size_t)(i0 + r0s) * NN + kbase + c0s * 8;
  const u16* gA1 = Am + (size_t)(i0 + r1s) * NN + kbase + c1s * 8;
  const u16* gB0 = ATm + (size_t)(j0 + r0s) * NN + kbase + c0s * 8;
  const u16* gB1 = ATm + (size_t)(j0 + r1s) * NN + kbase + c1s * 8;
  u16* lA0 = smem + (w * 2 + 0) * 512;
  u16* lA1 = smem + (w * 2 + 1) * 512;
  u16* lB0 = smem + 4096 + (w * 2 + 0) * 512;
  u16* lB1 = smem + 4096 + (w * 2 + 1) * 512;

  // fragment read offsets (u16 elements); row-swizzle const = (cl>>1)&3
  // (tile-base rows are multiples of 16 so they don't affect (row>>1)&3)
  const int swz = g ^ ((cl >> 1) & 3);
  int aoff[4], boff[4];
#pragma unroll
  for (int tm = 0; tm < 4; ++tm)
    aoff[tm] = (wm * 64 + tm * 16 + cl) * 32 + swz * 8;
#pragma unroll
  for (int tn = 0; tn < 4; ++tn)
    boff[tn] = 4096 + (wn * 64 + tn * 16 + cl) * 32 + swz * 8;

  floatx4 acc[4][4] = {};

  for (int k0 = 0; k0 < 1024; k0 += 32) {
    __syncthreads();  // previous iter's frag reads done before overwrite
    load_lds16(gA0 + k0, lA0);
    load_lds16(gA1 + k0, lA1);
    load_lds16(gB0 + k0, lB0);
    load_lds16(gB1 + k0, lB1);
    __syncthreads();  // compiler drains vmcnt before s_barrier

    short8 af[4], bfr[4];
#pragma unroll
    for (int tm = 0; tm < 4; ++tm)
      af[tm] = *(const short8*)(smem + aoff[tm]);
#pragma unroll
    for (int tn = 0; tn < 4; ++tn)
      bfr[tn] = *(const short8*)(smem + boff[tn]);
#pragma unroll
    for (int tm = 0; tm < 4; ++tm)
#pragma unroll
      for (int tn = 0; tn < 4; ++tn)
        acc[tm][tn] = __builtin_amdgcn_mfma_f32_16x16x32_bf16(
            af[tm], bfr[tn], acc[tm][tn], 0, 0, 0);
  }

  // epilogue: tri[i0+r] += sum_c C[r][c] * A^T[i0+r][j0+c]
  __syncthreads();
  // stage T[r][c] = AbfT[i0+r][j0+c] as [128][136] u16 (pad 8: 16B-aligned rows,
  // bank stride 4 -> 2-way max on the scalar reads)
#pragma unroll
  for (int it = 0; it < 8; ++it) {
    const int idx = tid + it * 256;
    const int r = idx >> 4, co = (idx & 15) * 8;
    *(uint4*)(smem + r * 136 + co) =
        *(const uint4*)(ATm + (size_t)(i0 + r) * NN + j0 + co);
  }
  __syncthreads();

#pragma unroll
  for (int tm = 0; tm < 4; ++tm) {
#pragma unroll
    for (int reg = 0; reg < 4; ++reg) {
      const int rloc = wm * 64 + tm * 16 + g * 4 + reg;  // C/D: row=(lane>>4)*4+reg
      float v = 0.f;
#pragma unroll
      for (int tn = 0; tn < 4; ++tn) {
        const int cloc = wn * 64 + tn * 16 + cl;          // C/D: col=lane&15
        v += acc[tm][tn][reg] * bf2f(smem[rloc * 136 + cloc]);
      }
      v += __shfl_xor(v, 1);
      v += __shfl_xor(v, 2);
      v += __shfl_xor(v, 4);
      v += __shfl_xor(v, 8);
      if (cl == 0) atomicAdd(&triM[i0 + rloc], v);
    }
  }
}

// ---------------------------------------------------------------------------
// finalize: d = sum of 32 partials (contiguous float4 loads); c = tri/(d(d-1))
// with clamp; means; exps. single block, 1024 threads.
// ---------------------------------------------------------------------------
__global__ __launch_bounds__(1024) void finalize_kernel(
    const float* __restrict__ degp, const float* __restrict__ tri,
    float* __restrict__ out) {
  __shared__ float red[32];
  const int t = threadIdx.x;
  float sdd = 0.f, scc = 0.f;
  for (int r = t; r < NN; r += 1024) {
    float d1 = 0.f, d2 = 0.f;
#pragma unroll
    for (int p = 0; p < 8; ++p) {
      const float4 v1 = *(const float4*)(degp + r * 32 + p * 4);
      const float4 v2 = *(const float4*)(degp + 32 * NN + r * 32 + p * 4);
      d1 += v1.x + v1.y + v1.z + v1.w;
      d2 += v2.x + v2.y + v2.z + v2.w;
    }
    const float t1 = tri[r], t2 = tri[NN + r];
    const float e1 = d1 < 2.f ? 1.f : d1;
    const float e2 = d2 < 2.f ? 1.f : d2;
    sdd += fabsf(d1 - d2);
    scc += fabsf(t1 / (e1 * (e1 - 1.f)) - t2 / (e2 * (e2 - 1.f)));
  }
#pragma unroll
  for (int m = 1; m < 64; m <<= 1) {
    sdd += __shfl_xor(sdd, m);
    scc += __shfl_xor(scc, m);
  }
  const int wv = t >> 6, ln = t & 63;
  if (ln == 0) { red[wv] = sdd; red[16 + wv] = scc; }
  __syncthreads();
  if (t == 0) {
    float a = 0.f, b = 0.f;
#pragma unroll
    for (int i = 0; i < 16; ++i) { a += red[i]; b += red[16 + i]; }
    const float ds = expf(-a * (1.f / (float)NN));
    const float cs = expf(-b * (1.f / (float)NN));
    out[0] = ds;
    out[1] = cs;
    out[2] = 0.5f * (ds + cs);
  }
}

extern "C" void kernel_launch(void* const* d_in, const int* in_sizes, int n_in,
                              void* d_out, int out_size, void* d_ws, size_t ws_size,
                              hipStream_t stream) {
  (void)in_sizes; (void)n_in; (void)out_size; (void)ws_size;
  const float* A1 = (const float*)d_in[0];
  const float* A2 = (const float*)d_in[1];
  float* out = (float*)d_out;

  // workspace layout (bytes):
  //   Abf  [2][2048*2048] u16 : 0          .. 16777216
  //   AbfT [2][2048*2048] u16 : 16777216   .. 33554432
  //   tri  [2][2048] f32      : 33554432   .. 33570816
  //   degp [2][2048][32] f32  : 33570816   .. 34095104
  u16* Abf = (u16*)d_ws;
  u16* AbfT = Abf + 2 * (size_t)NN * NN;
  float* tri = (float*)(AbfT + 2 * (size_t)NN * NN);
  float* degp = tri + 2 * NN;

  prep_kernel<<<dim3(32, 32, 2), 256, 0, stream>>>(A1, A2, Abf, AbfT, degp, tri);
  gemm_tri_kernel<<<dim3(16, 16, 4), 256, 0, stream>>>(Abf, AbfT, tri);
  finalize_kernel<<<1, 1024, 0, stream>>>(degp, tri, out);
}

// Round 3
// 127.994 us; speedup vs baseline: 1.2070x; 1.2070x over previous
//
#include <hip/hip_runtime.h>

#define NN 2048

typedef unsigned short u16;
typedef __attribute__((ext_vector_type(8))) short short8;
typedef __attribute__((ext_vector_type(4))) float floatx4;

__device__ __forceinline__ u16 f2bf(float f) {
  unsigned u = __float_as_uint(f);
  u += 0x7FFF + ((u >> 16) & 1);   // RNE
  return (u16)(u >> 16);
}

__device__ __forceinline__ float bf2f(u16 h) {
  return __uint_as_float(((unsigned)h) << 16);
}

// async global->LDS, 16B per lane. LDS dest = wave-uniform base + lane*16.
__device__ __forceinline__ void load_lds16(const u16* g, u16* l) {
  __builtin_amdgcn_global_load_lds(
      (const __attribute__((address_space(1))) unsigned int*)g,
      (__attribute__((address_space(3))) unsigned int*)l,
      16, 0, 0);
}

// ---------------------------------------------------------------------------
// prep: fp32 -> bf16 (Abf row-major + AbfT transposed), fp32 row-sum partials
// degp[mat][row][32] (contiguous per row for finalize), zero tri.
// grid (32,32,2), block 256. Tile 64x64.
// ---------------------------------------------------------------------------
__global__ __launch_bounds__(256) void prep_kernel(
    const float* __restrict__ A1, const float* __restrict__ A2,
    u16* __restrict__ Abf, u16* __restrict__ AbfT,
    float* __restrict__ degp, float* __restrict__ tri) {
  __shared__ u16 Tl[64][68];  // pad 4 -> bounded conflicts on transposed reads
  const int bx = blockIdx.x, by = blockIdx.y, bz = blockIdx.z;
  const float* __restrict__ A = bz ? A2 : A1;
  u16* __restrict__ ab = Abf + (size_t)bz * (NN * (size_t)NN);
  u16* __restrict__ at = AbfT + (size_t)bz * (NN * (size_t)NN);
  float* __restrict__ dp = degp + (size_t)bz * (32 * NN);
  const int t = threadIdx.x;
  const int r0 = by * 64, c0 = bx * 64;
  const int rs = t >> 4, cs = t & 15;

  if (bx == 0 && t < 64) tri[bz * NN + by * 64 + t] = 0.f;

#pragma unroll
  for (int it = 0; it < 4; ++it) {
    const int r = it * 16 + rs;
    const float4 fv = *(const float4*)(A + (size_t)(r0 + r) * NN + c0 + cs * 4);
    ushort4 b;
    b.x = f2bf(fv.x); b.y = f2bf(fv.y); b.z = f2bf(fv.z); b.w = f2bf(fv.w);
    *(ushort4*)(ab + (size_t)(r0 + r) * NN + c0 + cs * 4) = b;
    Tl[r][cs * 4 + 0] = b.x; Tl[r][cs * 4 + 1] = b.y;
    Tl[r][cs * 4 + 2] = b.z; Tl[r][cs * 4 + 3] = b.w;
    // exact fp32 row-sum partial over this 64-col slab
    float s = fv.x + fv.y + fv.z + fv.w;
    s += __shfl_xor(s, 1); s += __shfl_xor(s, 2);
    s += __shfl_xor(s, 4); s += __shfl_xor(s, 8);
    if (cs == 0) dp[(r0 + r) * 32 + bx] = s;
  }
  __syncthreads();
#pragma unroll
  for (int it = 0; it < 4; ++it) {
    const int c = it * 16 + rs;
    ushort4 b;
    b.x = Tl[cs * 4 + 0][c]; b.y = Tl[cs * 4 + 1][c];
    b.z = Tl[cs * 4 + 2][c]; b.w = Tl[cs * 4 + 3][c];
    *(ushort4*)(at + (size_t)(c0 + c) * NN + r0 + cs * 4) = b;
  }
}

// ---------------------------------------------------------------------------
// gemm_tri: tri[i] += sum_j (A@A)_{ij} * A_{ji}, fused; never materializes A@A.
// 128x128 C-tile per block, BK=32, 4 waves (2x2), 4x4 MFMA 16x16x32 per wave.
// SOFTWARE-PIPELINED: double-buffered LDS (2 x 16 KB), raw s_barrier + manual
// s_waitcnt vmcnt(4): iter k+1's global_load_lds issue BEFORE waiting on iter
// k's loads, hiding global->LDS latency behind the previous compute phase.
// Correctness: frag ds_reads are lgkmcnt-drained before each wave's MFMAs,
// which precede its barrier -> buffer p^1 is quiescent when overwritten.
// grid (16,16,2), block 256.
// ---------------------------------------------------------------------------
__global__ __launch_bounds__(256) void gemm_tri_kernel(
    const u16* __restrict__ Abf, const u16* __restrict__ AbfT,
    float* __restrict__ tri) {
  // loop: buf0 [0,8192) u16, buf1 [8192,16384); each buf: As 4096 + Bs 4096.
  // epilogue reuses [0,17408) as T 128x136.
  __shared__ u16 smem[17408];

  const int tid = threadIdx.x;
  const int w = tid >> 6, lane = tid & 63;
  const int wm = w >> 1, wn = w & 1;
  const int cl = lane & 15, g = lane >> 4;
  const int i0 = blockIdx.y * 128, j0 = blockIdx.x * 128;
  const size_t mat = (size_t)blockIdx.z * (NN * (size_t)NN);
  const u16* __restrict__ Am = Abf + mat;
  const u16* __restrict__ ATm = AbfT + mat;
  float* __restrict__ triM = tri + blockIdx.z * NN;

  // staging: wave w stages 2 slices for As, 2 for Bs per K-step.
  // LDS slot s (16B) -> row = s>>2, stored-chunk c' = s&3 holds global chunk
  // c = c' ^ ((row>>1)&3)  (global-side XOR swizzle -> frag reads conflict-free)
  const int s0 = (w * 2 + 0) * 64 + lane;
  const int s1 = (w * 2 + 1) * 64 + lane;
  const int r0s = s0 >> 2, c0s = (s0 & 3) ^ ((r0s >> 1) & 3);
  const int r1s = s1 >> 2, c1s = (s1 & 3) ^ ((r1s >> 1) & 3);
  const u16* gA0 = Am + (size_t)(i0 + r0s) * NN + c0s * 8;
  const u16* gA1 = Am + (size_t)(i0 + r1s) * NN + c1s * 8;
  const u16* gB0 = ATm + (size_t)(j0 + r0s) * NN + c0s * 8;
  const u16* gB1 = ATm + (size_t)(j0 + r1s) * NN + c1s * 8;
  const int sA0 = (w * 2 + 0) * 512, sA1 = (w * 2 + 1) * 512;
  const int sB0 = 4096 + sA0, sB1 = 4096 + sA1;

  // fragment read offsets (u16 elements) within a buffer
  const int swz = g ^ ((cl >> 1) & 3);   // 2-bit XOR, swz in 0..3
  int aoff[4], boff[4];
#pragma unroll
  for (int tm = 0; tm < 4; ++tm)
    aoff[tm] = (wm * 64 + tm * 16 + cl) * 32 + swz * 8;
#pragma unroll
  for (int tn = 0; tn < 4; ++tn)
    boff[tn] = 4096 + (wn * 64 + tn * 16 + cl) * 32 + swz * 8;

  floatx4 acc[4][4] = {};

  // preamble: iter 0 -> buf 0
  {
    u16* base = smem;
    load_lds16(gA0, base + sA0);
    load_lds16(gA1, base + sA1);
    load_lds16(gB0, base + sB0);
    load_lds16(gB1, base + sB1);
  }

  for (int it = 0; it < 64; ++it) {
    const int p = it & 1;
    asm volatile("" ::: "memory");
    __builtin_amdgcn_s_barrier();      // all waves done reading buf p^1
    asm volatile("" ::: "memory");
    if (it < 63) {
      const int kk = (it + 1) * 32;
      u16* base = smem + (p ^ 1) * 8192;
      load_lds16(gA0 + kk, base + sA0);
      load_lds16(gA1 + kk, base + sA1);
      load_lds16(gB0 + kk, base + sB0);
      load_lds16(gB1 + kk, base + sB1);
      __builtin_amdgcn_s_waitcnt(0x0F74);  // vmcnt(4): iter-it loads landed
    } else {
      __builtin_amdgcn_s_waitcnt(0x0F70);  // vmcnt(0): last iter
    }
    asm volatile("" ::: "memory");
    __builtin_amdgcn_s_barrier();      // everyone's iter-it loads landed
    asm volatile("" ::: "memory");

    const int pb = p * 8192;
    short8 af[4], bfr[4];
#pragma unroll
    for (int tm = 0; tm < 4; ++tm)
      af[tm] = *(const short8*)(smem + pb + aoff[tm]);
#pragma unroll
    for (int tn = 0; tn < 4; ++tn)
      bfr[tn] = *(const short8*)(smem + pb + boff[tn]);
#pragma unroll
    for (int tm = 0; tm < 4; ++tm)
#pragma unroll
      for (int tn = 0; tn < 4; ++tn)
        acc[tm][tn] = __builtin_amdgcn_mfma_f32_16x16x32_bf16(
            af[tm], bfr[tn], acc[tm][tn], 0, 0, 0);
  }

  // epilogue: tri[i0+r] += sum_c C[r][c] * A^T[i0+r][j0+c]
  __syncthreads();
  // stage T[r][c] = AbfT[i0+r][j0+c] as [128][136] u16
#pragma unroll
  for (int it = 0; it < 8; ++it) {
    const int idx = tid + it * 256;
    const int r = idx >> 4, co = (idx & 15) * 8;
    *(uint4*)(smem + r * 136 + co) =
        *(const uint4*)(ATm + (size_t)(i0 + r) * NN + j0 + co);
  }
  __syncthreads();

#pragma unroll
  for (int tm = 0; tm < 4; ++tm) {
#pragma unroll
    for (int reg = 0; reg < 4; ++reg) {
      const int rloc = wm * 64 + tm * 16 + g * 4 + reg;  // C/D: row=(lane>>4)*4+reg
      float v = 0.f;
#pragma unroll
      for (int tn = 0; tn < 4; ++tn) {
        const int cloc = wn * 64 + tn * 16 + cl;          // C/D: col=lane&15
        v += acc[tm][tn][reg] * bf2f(smem[rloc * 136 + cloc]);
      }
      v += __shfl_xor(v, 1);
      v += __shfl_xor(v, 2);
      v += __shfl_xor(v, 4);
      v += __shfl_xor(v, 8);
      if (cl == 0) atomicAdd(&triM[i0 + rloc], v);
    }
  }
}

// ---------------------------------------------------------------------------
// finalize stage 1: grid 16 x 1024 threads; block b reduces rows [b*128,+128):
// deg sums (8 lanes/row over degp[row][32]), |d1-d2| and |c1-c2| partials to
// part[b*2 + {0,1}] (slot per block, no pre-zero needed).
// ---------------------------------------------------------------------------
__global__ __launch_bounds__(1024) void finalize1_kernel(
    const float* __restrict__ degp, const float* __restrict__ tri,
    float* __restrict__ part) {
  __shared__ float red[32];
  const int t = threadIdx.x;
  const int r = blockIdx.x * 128 + (t >> 3);   // row
  const int q = (t & 7) * 4;                   // degp chunk
  const float4 v1 = *(const float4*)(degp + (size_t)r * 32 + q);
  const float4 v2 = *(const float4*)(degp + 32 * NN + (size_t)r * 32 + q);
  float d1 = v1.x + v1.y + v1.z + v1.w;
  float d2 = v2.x + v2.y + v2.z + v2.w;
#pragma unroll
  for (int m = 1; m < 8; m <<= 1) {
    d1 += __shfl_xor(d1, m);
    d2 += __shfl_xor(d2, m);
  }
  float sdd = 0.f, scc = 0.f;
  if ((t & 7) == 0) {
    const float t1 = tri[r], t2 = tri[NN + r];
    const float e1 = d1 < 2.f ? 1.f : d1;
    const float e2 = d2 < 2.f ? 1.f : d2;
    sdd = fabsf(d1 - d2);
    scc = fabsf(t1 / (e1 * (e1 - 1.f)) - t2 / (e2 * (e2 - 1.f)));
  }
#pragma unroll
  for (int m = 8; m < 64; m <<= 1) {
    sdd += __shfl_xor(sdd, m);
    scc += __shfl_xor(scc, m);
  }
  const int wv = t >> 6, ln = t & 63;
  if (ln == 0) { red[wv] = sdd; red[16 + wv] = scc; }
  __syncthreads();
  if (t == 0) {
    float a = 0.f, b = 0.f;
#pragma unroll
    for (int i = 0; i < 16; ++i) { a += red[i]; b += red[16 + i]; }
    part[blockIdx.x * 2 + 0] = a;
    part[blockIdx.x * 2 + 1] = b;
  }
}

__global__ void finalize2_kernel(const float* __restrict__ part,
                                 float* __restrict__ out) {
  if (threadIdx.x == 0) {
    float a = 0.f, b = 0.f;
#pragma unroll
    for (int i = 0; i < 16; ++i) { a += part[i * 2]; b += part[i * 2 + 1]; }
    const float ds = expf(-a * (1.f / (float)NN));
    const float cs = expf(-b * (1.f / (float)NN));
    out[0] = ds;
    out[1] = cs;
    out[2] = 0.5f * (ds + cs);
  }
}

extern "C" void kernel_launch(void* const* d_in, const int* in_sizes, int n_in,
                              void* d_out, int out_size, void* d_ws, size_t ws_size,
                              hipStream_t stream) {
  (void)in_sizes; (void)n_in; (void)out_size; (void)ws_size;
  const float* A1 = (const float*)d_in[0];
  const float* A2 = (const float*)d_in[1];
  float* out = (float*)d_out;

  // workspace layout:
  //   Abf  [2][2048*2048] u16
  //   AbfT [2][2048*2048] u16
  //   tri  [2][2048] f32
  //   degp [2][2048][32] f32
  //   part [32] f32
  u16* Abf = (u16*)d_ws;
  u16* AbfT = Abf + 2 * (size_t)NN * NN;
  float* tri = (float*)(AbfT + 2 * (size_t)NN * NN);
  float* degp = tri + 2 * NN;
  float* part = degp + 2 * 32 * NN;

  prep_kernel<<<dim3(32, 32, 2), 256, 0, stream>>>(A1, A2, Abf, AbfT, degp, tri);
  gemm_tri_kernel<<<dim3(16, 16, 2), 256, 0, stream>>>(Abf, AbfT, tri);
  finalize1_kernel<<<16, 1024, 0, stream>>>(degp, tri, part);
  finalize2_kernel<<<1, 64, 0, stream>>>(part, out);
}